// Round 6
// baseline (66.548 us; speedup 1.0000x reference)
//
#include <hip/hip_runtime.h>
#include <math.h>

// SCTC-SB loss, round 6: two-kernel structure.
//  - prep: per-(pair,t) 3-class softmax -> ws as float4(q2, q0, q1-q0, 0).
//  - scan: 1 wave per block (uniform address -> s_load SGPR probs), fp32
//    linear-domain recursion, 14 VALU/step, no readlane/transcendental in
//    the serial loop. 8-step groups, SGPR double-buffer, renorm per group.
//  - fused deterministic final reduction via counter (prep zeroes it).

#define LOG2E 1.4426950408889634f
#define LN2d 0.69314718055994530942

constexpr int Bc = 16, Tc = 500, Sc = 100, Fc = 35;
constexpr int NPAIR = Bc * Fc;  // 560
constexpr int TP = 512;         // padded T (prob rows per pair)
constexpr int EXPB = 237;       // renorm target biased exponent (2^110)

// lane l gets lane l-1's value; lane 0 gets 0.0f
__device__ __forceinline__ float dpp_shr1(float v) {
  return __int_as_float(__builtin_amdgcn_update_dpp(
      0, __float_as_int(v), 0x138 /*wave_shr:1*/, 0xF, 0xF, false));
}
__device__ __forceinline__ float rdl(float v, int j) {
  return __int_as_float(__builtin_amdgcn_readlane(__float_as_int(v), j));
}
template <int C>
__device__ __forceinline__ int dppmax(int v) {
  int t = __builtin_amdgcn_update_dpp(v, v, C, 0xF, 0xF, false);
  return max(v, t);
}

__global__ __launch_bounds__(256) void sctc_prep(
    const float* __restrict__ logits,       // (B,T,F)
    const float* __restrict__ blank_logit,  // (1,)
    float4* __restrict__ probs,             // (NPAIR, TP)
    int* __restrict__ cnt) {
  if (blockIdx.x == 0 && blockIdx.y == 0 && threadIdx.x == 0) *cnt = 0;
  const int t = blockIdx.x * 256 + threadIdx.x;
  const int p = blockIdx.y;
  if (t >= Tc) return;
  const int b = p / Fc, f = p - b * Fc;
  const float bl = blank_logit[0] * LOG2E;
  const float x = logits[((size_t)b * Tc + t) * Fc + f] * LOG2E;
  const float m = fmaxf(fabsf(x), bl);
  const float u0 = exp2f(-x - m), u1 = exp2f(x - m), u2 = exp2f(bl - m);
  const float rz = 1.0f / (u0 + u1 + u2);
  const float q0 = u0 * rz, q1 = u1 * rz, q2 = u2 * rz;
  probs[(size_t)p * TP + t] = make_float4(q2, q0, q1 - q0, 0.0f);
}

__global__ __launch_bounds__(64) void sctc_scan(
    const float4* __restrict__ probs,    // (NPAIR, TP)
    const int* __restrict__ targets,     // (B,S,F) 0/1
    const int* __restrict__ in_len,      // (B,)
    const int* __restrict__ tgt_len,     // (B,)
    float* __restrict__ part,            // (NPAIR,)
    int* __restrict__ cnt,
    float* __restrict__ out) {
  const int lane = threadIdx.x;  // one wave per block
  const int p = blockIdx.x;
  const int b = p / Fc, f = p - b * Fc;
  const int Tin = in_len[b];  // uniform
  const int L = tgt_len[b];   // uniform

  // lane l holds states e = 4l..4l+3 as a0..a3.
  const int tbase = b * Sc * Fc + f;
  const int t0 = targets[tbase + min(2 * lane, Sc - 1) * Fc];
  const int t1 = targets[tbase + min(2 * lane + 1, Sc - 1) * Fc];
  const int tprev = __shfl_up(t1, 1);  // tgt[2l-1] (init only)
  const float bt0f = t0 ? 1.0f : 0.0f, bt1f = t1 ? 1.0f : 0.0f;
  const float sk1f = (lane == 0 || t0 != tprev) ? 1.0f : 0.0f;
  const float sk3f = (t1 != t0) ? 1.0f : 0.0f;

  const int e_hi = 2 * L + 1, twoLm1 = 2 * L - 1;
  const int e0 = 4 * lane;
  const bool in0 = e0 <= e_hi, in1 = e0 + 1 <= e_hi, in2 = e0 + 2 <= e_hi,
             in3 = e0 + 3 <= e_hi;

  const float4* __restrict__ pp = probs + (size_t)p * TP;

  float a0 = 0.0f, a1 = 0.0f, a2 = 0.0f, a3 = 0.0f;
  int off = -110;  // true_alpha = stored * 2^off
  {
    const float4 c0 = pp[0];
    const float scl = __int_as_float((110 + 127) << 23);  // 2^110
    if (lane == 0) {
      a0 = c0.x * scl;
      a1 = fmaf(bt0f, c0.z, c0.y) * scl;  // (q0 + bt0*(q1-q0)) * 2^110
    }
  }

#define STEP(G)                                       \
  {                                                   \
    const float vd = (G).z;                           \
    const float po0 = fmaf(bt0f, vd, (G).y);          \
    const float po1 = fmaf(bt1f, vd, (G).y);          \
    const float pr3 = dpp_shr1(a3); /* alpha[4l-1] */ \
    const float s01 = a0 + a1;                        \
    const float s12 = a1 + a2;                        \
    const float s23 = a2 + a3;                        \
    const float t0v = a0 + pr3;                       \
    const float t2v = fmaf(pr3, sk1f, s01);           \
    const float t3v = fmaf(a1, sk3f, s23);            \
    a0 = t0v * (G).x;                                 \
    a1 = t2v * po0;                                   \
    a2 = s12 * (G).x;                                 \
    a3 = t3v * po1;                                   \
  }

#define RENORM(TT)                                                     \
  {                                                                    \
    const int elo = twoLm1 - 2 * (Tin - 1 - (TT));                     \
    int ex0 = (in0 && e0 >= elo) ? (__float_as_int(a0) >> 23) : 0;     \
    int ex1 = (in1 && e0 + 1 >= elo) ? (__float_as_int(a1) >> 23) : 0; \
    int ex2 = (in2 && e0 + 2 >= elo) ? (__float_as_int(a2) >> 23) : 0; \
    int ex3 = (in3 && e0 + 3 >= elo) ? (__float_as_int(a3) >> 23) : 0; \
    int mm = max(max(ex0, ex1), max(ex2, ex3));                        \
    mm = dppmax<0x111>(mm);                                            \
    mm = dppmax<0x112>(mm);                                            \
    mm = dppmax<0x114>(mm);                                            \
    mm = dppmax<0x118>(mm);                                            \
    mm = dppmax<0x142>(mm);                                            \
    mm = dppmax<0x143>(mm);                                            \
    const int mw = __builtin_amdgcn_readlane(mm, 63);                  \
    int k = EXPB - mw;                                                 \
    k = min(k, 126);                                                   \
    const float sc = __int_as_float((k + 127) << 23);                  \
    a0 *= sc; a1 *= sc; a2 *= sc; a3 *= sc;                            \
    off -= k;                                                          \
  }

#define LOAD8(DST, TB)                       \
  _Pragma("unroll") for (int i_ = 0; i_ < 8; ++i_) (DST)[i_] = pp[(TB) + i_];
#define PROC8(SRC)                           \
  _Pragma("unroll") for (int i_ = 0; i_ < 8; ++i_) STEP((SRC)[i_]);

  // groups of 8 steps; group g covers t = 1+8g .. 8+8g. Tin>=300 => NG>=37.
  float4 c[8], n[8];
  LOAD8(c, 1);
  const int NG = (Tin - 1) >> 3;
  int g = 0;
  while (g + 1 < NG) {
    LOAD8(n, 1 + (g + 1) * 8);  // prefetch next group
    PROC8(c);
    RENORM(8 * g + 8);
    LOAD8(c, 1 + (g + 2) * 8);  // prefetch (valid mem: <= 8*(NG+1)+? < TP)
    PROC8(n);
    RENORM(8 * g + 16);
    g += 2;
  }
  const int tail = (Tin - 1) & 7;
  if (g < NG) {  // one full group left in c
    LOAD8(n, 1 + (g + 1) * 8);
    PROC8(c);
    RENORM(8 * g + 8);
#pragma unroll
    for (int i_ = 0; i_ < 8; ++i_)
      if (i_ < tail) STEP(n[i_]);
  } else {  // tail data already in c
#pragma unroll
    for (int i_ = 0; i_ < 8; ++i_)
      if (i_ < tail) STEP(c[i_]);
  }

  // readout: ll = log(alpha[2L] + alpha[2L-1]) + off*ln2
  const int r1 = 2 * L, r2 = 2 * L - 1;
  const float w1 = (r1 & 2) ? a2 : a0;  // even state -> reg 0 or 2
  const float w2 = (r2 & 2) ? a3 : a1;  // odd state  -> reg 1 or 3
  const float aL = rdl(w1, r1 >> 2);
  const float aL1 = rdl(w2, r2 >> 2);
  const float ssum = aL + aL1;
  float val = 0.0f;
  if (ssum > 0.0f) {
    const int bits = __float_as_int(ssum);
    const int ex = ((bits >> 23) & 255) - 126;
    const float mant = __int_as_float((bits & 0x007fffff) | 0x3f000000);
    const double ll2 = (double)(ex + off) + (double)log2f(mant);
    double ld = -ll2 * LN2d;
    if (ld > 0.5e30) ld = 0.0;  // zero_infinity
    val = (float)(ld / (double)L) * (1.0f / (float)NPAIR);
  }
  if (lane == 0) part[p] = val;

  // fused deterministic reduction: last block sums in fixed order.
  __threadfence();
  int last = 0;
  if (lane == 0) last = (atomicAdd(cnt, 1) == NPAIR - 1) ? 1 : 0;
  last = __shfl(last, 0);
  if (last) {
    __threadfence();
    float s = 0.0f;
    for (int i = lane; i < NPAIR; i += 64)
      s += __hip_atomic_load(&part[i], __ATOMIC_RELAXED,
                             __HIP_MEMORY_SCOPE_AGENT);
    for (int o = 32; o >= 1; o >>= 1) s += __shfl_xor(s, o);
    if (lane == 0) out[0] = s;
  }
#undef STEP
#undef RENORM
#undef LOAD8
#undef PROC8
}

extern "C" void kernel_launch(void* const* d_in, const int* in_sizes, int n_in,
                              void* d_out, int out_size, void* d_ws,
                              size_t ws_size, hipStream_t stream) {
  const float* logits = (const float*)d_in[0];
  const float* blank_logit = (const float*)d_in[1];
  const int* targets = (const int*)d_in[2];
  const int* in_len = (const int*)d_in[3];
  const int* tgt_len = (const int*)d_in[4];
  float* out = (float*)d_out;

  float4* probs = (float4*)d_ws;  // 560*512*16 B = 4.59 MB
  float* part = (float*)((char*)d_ws + sizeof(float4) * (size_t)NPAIR * TP);
  int* cnt = (int*)(part + NPAIR);

  sctc_prep<<<dim3(2, NPAIR), 256, 0, stream>>>(logits, blank_logit, probs,
                                                cnt);
  sctc_scan<<<NPAIR, 64, 0, stream>>>(probs, targets, in_len, tgt_len, part,
                                      cnt, out);
}

// Round 7
// 32.710 us; speedup vs baseline: 2.0345x; 2.0345x over previous
//
#include <hip/hip_runtime.h>
#include <math.h>

// SCTC-SB loss, round 7: single-wave-per-pair scan; per-64-t chunk softmax
// computed in-kernel (per-lane, parallel), staged to LDS via ds_write_b128,
// consumed by one wave-uniform ds_read_b128 per step (no readlane, no SGPR
// hazards, no HBM round-trip for probs). fp32 linear domain, renorm/8 steps.

#define LOG2E 1.4426950408889634f
#define LN2d 0.69314718055994530942

constexpr int Bc = 16, Tc = 500, Sc = 100, Fc = 35;
constexpr int NPAIR = Bc * Fc;  // 560
constexpr int EXPB = 237;       // renorm target biased exponent (2^110)

// lane l gets lane l-1's value; lane 0 gets 0.0f
__device__ __forceinline__ float dpp_shr1(float v) {
  return __int_as_float(__builtin_amdgcn_update_dpp(
      0, __float_as_int(v), 0x138 /*wave_shr:1*/, 0xF, 0xF, false));
}
__device__ __forceinline__ float rdl(float v, int j) {
  return __int_as_float(__builtin_amdgcn_readlane(__float_as_int(v), j));
}
template <int C>
__device__ __forceinline__ int dppmax(int v) {
  int t = __builtin_amdgcn_update_dpp(v, v, C, 0xF, 0xF, false);
  return max(v, t);
}

__global__ __launch_bounds__(64) void sctc_scan(
    const float* __restrict__ logits,       // (B,T,F)
    const float* __restrict__ blank_logit,  // (1,)
    const int* __restrict__ targets,        // (B,S,F) 0/1
    const int* __restrict__ in_len,         // (B,)
    const int* __restrict__ tgt_len,        // (B,)
    float* __restrict__ part) {             // (NPAIR,)
  __shared__ float4 lds[2][64];
  const int lane = threadIdx.x;  // one wave per block
  const int p = blockIdx.x;
  const int b = p / Fc, f = p - b * Fc;
  const int Tin = in_len[b];  // uniform
  const int L = tgt_len[b];   // uniform
  const float bl2 = blank_logit[0] * LOG2E;
  const float* __restrict__ lg = logits + (size_t)b * Tc * Fc + f;

  // lane l holds states e = 4l..4l+3 as a0..a3.
  const int tbase = b * Sc * Fc + f;
  const int t0 = targets[tbase + min(2 * lane, Sc - 1) * Fc];
  const int t1 = targets[tbase + min(2 * lane + 1, Sc - 1) * Fc];
  const int tprev = __shfl_up(t1, 1);  // tgt[2l-1] (init only)
  const float bt0f = t0 ? 1.0f : 0.0f, bt1f = t1 ? 1.0f : 0.0f;
  const float sk1f = (lane == 0 || t0 != tprev) ? 1.0f : 0.0f;
  const float sk3f = (t1 != t0) ? 1.0f : 0.0f;

  const int e_hi = 2 * L + 1, twoLm1 = 2 * L - 1;
  const int e0 = 4 * lane;
  const bool in0 = e0 <= e_hi, in1 = e0 + 1 <= e_hi, in2 = e0 + 2 <= e_hi,
             in3 = e0 + 3 <= e_hi;

  // 3-class softmax -> float4(q2, q0, q1-q0, 0)
  auto sm = [&](float xr) {
    const float x = xr * LOG2E;
    const float m = fmaxf(fabsf(x), bl2);
    const float u0 = exp2f(-x - m), u1 = exp2f(x - m), u2 = exp2f(bl2 - m);
    const float rz = 1.0f / (u0 + u1 + u2);
    const float q0 = u0 * rz, q1 = u1 * rz;
    return make_float4(u2 * rz, q0, q1 - q0, 0.0f);
  };

  float a0 = 0.0f, a1 = 0.0f, a2 = 0.0f, a3 = 0.0f;
  int off = -110;  // true_alpha = stored * 2^off
  {
    const float4 c0 = sm(lg[0]);
    const float scl = __int_as_float((110 + 127) << 23);  // 2^110
    if (lane == 0) {
      a0 = c0.x * scl;
      a1 = fmaf(bt0f, c0.z, c0.y) * scl;
    }
  }

#define STEP(G)                                       \
  {                                                   \
    const float vd = (G).z;                           \
    const float po0 = fmaf(bt0f, vd, (G).y);          \
    const float po1 = fmaf(bt1f, vd, (G).y);          \
    const float pr3 = dpp_shr1(a3); /* alpha[4l-1] */ \
    const float s01 = a0 + a1;                        \
    const float s12 = a1 + a2;                        \
    const float s23 = a2 + a3;                        \
    const float t0v = a0 + pr3;                       \
    const float t2v = fmaf(pr3, sk1f, s01);           \
    const float t3v = fmaf(a1, sk3f, s23);            \
    a0 = t0v * (G).x;                                 \
    a1 = t2v * po0;                                   \
    a2 = s12 * (G).x;                                 \
    a3 = t3v * po1;                                   \
  }

#define RENORM(TT)                                                     \
  {                                                                    \
    const int elo = twoLm1 - 2 * (Tin - 1 - (TT));                     \
    int ex0 = (in0 && e0 >= elo) ? (__float_as_int(a0) >> 23) : 0;     \
    int ex1 = (in1 && e0 + 1 >= elo) ? (__float_as_int(a1) >> 23) : 0; \
    int ex2 = (in2 && e0 + 2 >= elo) ? (__float_as_int(a2) >> 23) : 0; \
    int ex3 = (in3 && e0 + 3 >= elo) ? (__float_as_int(a3) >> 23) : 0; \
    int mm = max(max(ex0, ex1), max(ex2, ex3));                        \
    mm = dppmax<0x111>(mm);                                            \
    mm = dppmax<0x112>(mm);                                            \
    mm = dppmax<0x114>(mm);                                            \
    mm = dppmax<0x118>(mm);                                            \
    mm = dppmax<0x142>(mm);                                            \
    mm = dppmax<0x143>(mm);                                            \
    const int mw = __builtin_amdgcn_readlane(mm, 63);                  \
    int k = EXPB - mw;                                                 \
    k = min(k, 126);                                                   \
    const float sc = __int_as_float((k + 127) << 23);                  \
    a0 *= sc; a1 *= sc; a2 *= sc; a3 *= sc;                            \
    off -= k;                                                          \
  }

  // prologue: stage chunk0 (t=1..64), preload raw logit for chunk1
  float xraw = lg[min(1 + lane, Tc - 1) * Fc];
  lds[0][lane] = sm(xraw);
  xraw = lg[min(65 + lane, Tc - 1) * Fc];
  asm volatile("s_waitcnt lgkmcnt(0)" ::: "memory");

  int buf = 0;
  for (int tb = 1; tb < Tin; tb += 64) {
    // stage chunk for tb+64 into other buffer; preload raw for tb+128
    if (tb + 64 < Tin) {
      lds[buf ^ 1][lane] = sm(xraw);
      xraw = lg[min(tb + 128 + lane, Tc - 1) * Fc];
    }
    const float4* __restrict__ cp = &lds[buf][0];
    if (tb + 64 <= Tin) {  // full 64 steps
#pragma unroll
      for (int grp = 0; grp < 8; ++grp) {
        float4 g0 = cp[8 * grp + 0], g1 = cp[8 * grp + 1];
        float4 g2 = cp[8 * grp + 2], g3 = cp[8 * grp + 3];
        float4 g4 = cp[8 * grp + 4], g5 = cp[8 * grp + 5];
        float4 g6 = cp[8 * grp + 6], g7 = cp[8 * grp + 7];
        STEP(g0); STEP(g1); STEP(g2); STEP(g3);
        STEP(g4); STEP(g5); STEP(g6); STEP(g7);
        RENORM(tb + 8 * grp + 7);
      }
    } else {
      const int n = Tin - tb;  // 1..63 remaining steps
#pragma unroll
      for (int grp = 0; grp < 8; ++grp) {
        if (8 * grp >= n) break;  // wave-uniform
        float4 g[8];
#pragma unroll
        for (int i = 0; i < 8; ++i) g[i] = cp[8 * grp + i];
#pragma unroll
        for (int i = 0; i < 8; ++i) {
          if (8 * grp + i >= n) break;  // wave-uniform
          STEP(g[i]);
        }
        if (8 * grp + 8 <= n) RENORM(tb + 8 * grp + 7);
      }
    }
    buf ^= 1;
    asm volatile("s_waitcnt lgkmcnt(0)" ::: "memory");
  }

  // readout: ll = log(alpha[2L] + alpha[2L-1]) + off*ln2
  const int r1 = 2 * L, r2 = 2 * L - 1;
  const float w1 = (r1 & 2) ? a2 : a0;  // even state -> reg 0 or 2
  const float w2 = (r2 & 2) ? a3 : a1;  // odd state  -> reg 1 or 3
  const float aL = rdl(w1, r1 >> 2);
  const float aL1 = rdl(w2, r2 >> 2);
  const float ssum = aL + aL1;
  float val = 0.0f;
  if (ssum > 0.0f) {
    const int bits = __float_as_int(ssum);
    const int ex = ((bits >> 23) & 255) - 126;
    const float mant = __int_as_float((bits & 0x007fffff) | 0x3f000000);
    const double ll2 = (double)(ex + off) + (double)log2f(mant);
    double ld = -ll2 * LN2d;
    if (ld > 0.5e30) ld = 0.0;  // zero_infinity
    val = (float)(ld / (double)L) * (1.0f / (float)NPAIR);
  }
  if (lane == 0) part[p] = val;
#undef STEP
#undef RENORM
}

__global__ __launch_bounds__(256) void sctc_reduce(const float* __restrict__ ws,
                                                   float* __restrict__ out) {
  const int tid = threadIdx.x;
  float s = 0.0f;
  for (int i = tid; i < NPAIR; i += 256) s += ws[i];
  for (int o = 32; o >= 1; o >>= 1) s += __shfl_down(s, o);
  __shared__ float partial[4];
  if ((tid & 63) == 0) partial[tid >> 6] = s;
  __syncthreads();
  if (tid == 0) out[0] = partial[0] + partial[1] + partial[2] + partial[3];
}

extern "C" void kernel_launch(void* const* d_in, const int* in_sizes, int n_in,
                              void* d_out, int out_size, void* d_ws,
                              size_t ws_size, hipStream_t stream) {
  const float* logits = (const float*)d_in[0];
  const float* blank_logit = (const float*)d_in[1];
  const int* targets = (const int*)d_in[2];
  const int* in_len = (const int*)d_in[3];
  const int* tgt_len = (const int*)d_in[4];
  float* part = (float*)d_ws;
  float* out = (float*)d_out;

  sctc_scan<<<NPAIR, 64, 0, stream>>>(logits, blank_logit, targets, in_len,
                                      tgt_len, part);
  sctc_reduce<<<1, 256, 0, stream>>>(part, out);
}

// Round 8
// 31.355 us; speedup vs baseline: 2.1224x; 1.0432x over previous
//
#include <hip/hip_runtime.h>
#include <math.h>

// SCTC-SB loss, round 8: pipelined scan.
//  - Deferred renorm: snapshot band-masked exponent max at group end; DPP max
//    tree overlaps next group's STEPs; scale applied 4 steps stale (safe:
//    target 2^90, worst drift 12*15 bits < 90+126; growth <= 2^122).
//  - Register double-buffer (A/B x 8 float4) of LDS prob groups: prefetch
//    group g+1 while stepping group g. No lgkmcnt barriers (DS is per-wave
//    FIFO; compiler inserts data waits).

#define LOG2E 1.4426950408889634f
#define LN2d 0.69314718055994530942

constexpr int Bc = 16, Tc = 500, Sc = 100, Fc = 35;
constexpr int NPAIR = Bc * Fc;  // 560
constexpr int EXPB = 217;       // renorm target biased exponent (2^90)

// lane l gets lane l-1's value; lane 0 gets 0.0f
__device__ __forceinline__ float dpp_shr1(float v) {
  return __int_as_float(__builtin_amdgcn_update_dpp(
      0, __float_as_int(v), 0x138 /*wave_shr:1*/, 0xF, 0xF, false));
}
__device__ __forceinline__ float rdl(float v, int j) {
  return __int_as_float(__builtin_amdgcn_readlane(__float_as_int(v), j));
}
template <int C>
__device__ __forceinline__ int dppmax(int v) {
  int t = __builtin_amdgcn_update_dpp(v, v, C, 0xF, 0xF, false);
  return max(v, t);
}

__global__ __launch_bounds__(64) void sctc_scan(
    const float* __restrict__ logits,       // (B,T,F)
    const float* __restrict__ blank_logit,  // (1,)
    const int* __restrict__ targets,        // (B,S,F) 0/1
    const int* __restrict__ in_len,         // (B,)
    const int* __restrict__ tgt_len,        // (B,)
    float* __restrict__ part) {             // (NPAIR,)
  __shared__ float4 lds[2][64];
  const int lane = threadIdx.x;  // one wave per block
  const int p = blockIdx.x;
  const int b = p / Fc, f = p - b * Fc;
  const int Tin = in_len[b];  // uniform
  const int L = tgt_len[b];   // uniform
  const float bl2 = blank_logit[0] * LOG2E;
  const float* __restrict__ lg = logits + (size_t)b * Tc * Fc + f;

  // lane l holds states e = 4l..4l+3 as a0..a3.
  const int tbase = b * Sc * Fc + f;
  const int t0 = targets[tbase + min(2 * lane, Sc - 1) * Fc];
  const int t1 = targets[tbase + min(2 * lane + 1, Sc - 1) * Fc];
  const int tprev = __shfl_up(t1, 1);  // tgt[2l-1] (init only)
  const float bt0f = t0 ? 1.0f : 0.0f, bt1f = t1 ? 1.0f : 0.0f;
  const float sk1f = (lane == 0 || t0 != tprev) ? 1.0f : 0.0f;
  const float sk3f = (t1 != t0) ? 1.0f : 0.0f;

  const int e_hi = 2 * L + 1, twoLm1 = 2 * L - 1;
  const int e0 = 4 * lane;
  const bool in0 = e0 <= e_hi, in1 = e0 + 1 <= e_hi, in2 = e0 + 2 <= e_hi,
             in3 = e0 + 3 <= e_hi;

  // 3-class softmax -> float4(q2, q0, q1-q0, 0)
  auto sm = [&](float xr) {
    const float x = xr * LOG2E;
    const float m = fmaxf(fabsf(x), bl2);
    const float u0 = exp2f(-x - m), u1 = exp2f(x - m), u2 = exp2f(bl2 - m);
    const float rz = 1.0f / (u0 + u1 + u2);
    const float q0 = u0 * rz, q1 = u1 * rz;
    return make_float4(u2 * rz, q0, q1 - q0, 0.0f);
  };

  float a0 = 0.0f, a1 = 0.0f, a2 = 0.0f, a3 = 0.0f;
  int off = -90;  // true_alpha = stored * 2^off
  {
    const float4 c0 = sm(lg[0]);
    const float scl = __int_as_float((90 + 127) << 23);  // 2^90
    if (lane == 0) {
      a0 = c0.x * scl;
      a1 = fmaf(bt0f, c0.z, c0.y) * scl;
    }
  }

#define STEP(G)                                       \
  {                                                   \
    const float vd = (G).z;                           \
    const float po0 = fmaf(bt0f, vd, (G).y);          \
    const float po1 = fmaf(bt1f, vd, (G).y);          \
    const float pr3 = dpp_shr1(a3); /* alpha[4l-1] */ \
    const float s01 = a0 + a1;                        \
    const float s12 = a1 + a2;                        \
    const float s23 = a2 + a3;                        \
    const float t0v = a0 + pr3;                       \
    const float t2v = fmaf(pr3, sk1f, s01);           \
    const float t3v = fmaf(a1, sk3f, s23);            \
    a0 = t0v * (G).x;                                 \
    a1 = t2v * po0;                                   \
    a2 = s12 * (G).x;                                 \
    a3 = t3v * po1;                                   \
  }

  int mm = 0;  // renorm snapshot (band-masked biased exponent max, local)

#define SNAP(TT)                                                          \
  {                                                                       \
    const int elo = twoLm1 - 2 * (Tin - 1 - (TT));                        \
    const int x0 = (in0 && e0 >= elo) ? (__float_as_int(a0) >> 23) : 0;   \
    const int x1 = (in1 && e0 + 1 >= elo) ? (__float_as_int(a1) >> 23) : 0; \
    const int x2 = (in2 && e0 + 2 >= elo) ? (__float_as_int(a2) >> 23) : 0; \
    const int x3 = (in3 && e0 + 3 >= elo) ? (__float_as_int(a3) >> 23) : 0; \
    mm = max(max(x0, x1), max(x2, x3));                                   \
  }

#define TREE                  \
  {                           \
    mm = dppmax<0x111>(mm);   \
    mm = dppmax<0x112>(mm);   \
    mm = dppmax<0x114>(mm);   \
    mm = dppmax<0x118>(mm);   \
    mm = dppmax<0x142>(mm);   \
    mm = dppmax<0x143>(mm);   \
  }

#define APPLY                                         \
  {                                                   \
    const int mw = __builtin_amdgcn_readlane(mm, 63); \
    int k = EXPB - mw;                                \
    k = min(max(k, -126), 126);                       \
    const float sc = __int_as_float((k + 127) << 23); \
    a0 *= sc; a1 *= sc; a2 *= sc; a3 *= sc;           \
    off -= k;                                         \
  }

// Process 8 steps from P while prefetching 8 float4s into Q from SRC.
// TREE (on previous snapshot) overlaps STEPs 0-3; APPLY mid-group; new SNAP
// at group end (TTLAST = time index of last step in this group).
#define GROUP(P, Q, SRC, TTLAST)                                        \
  {                                                                     \
    _Pragma("unroll") for (int i_ = 0; i_ < 8; ++i_) Q[i_] = (SRC)[i_]; \
    STEP(P[0]);                                                         \
    TREE;                                                               \
    STEP(P[1]);                                                         \
    STEP(P[2]);                                                         \
    STEP(P[3]);                                                         \
    APPLY;                                                              \
    STEP(P[4]);                                                         \
    STEP(P[5]);                                                         \
    STEP(P[6]);                                                         \
    STEP(P[7]);                                                         \
    SNAP(TTLAST);                                                       \
  }

  // prologue: stage chunk0 (t=1..64), preload raw logit for chunk1,
  // prefetch group 0 into A, take initial snapshot (t=0).
  float xraw = lg[min(1 + lane, Tc - 1) * Fc];
  lds[0][lane] = sm(xraw);
  xraw = lg[min(65 + lane, Tc - 1) * Fc];

  float4 A[8], B[8];
  {
    const float4* c0 = &lds[0][0];
#pragma unroll
    for (int i = 0; i < 8; ++i) A[i] = c0[i];
  }
  SNAP(0);

  int buf = 0;
  int tb = 1;
  for (; tb + 64 <= Tin; tb += 64) {
    if (tb + 64 < Tin) {
      lds[buf ^ 1][lane] = sm(xraw);
      xraw = lg[min(tb + 128 + lane, Tc - 1) * Fc];
    }
    const float4* cpA = &lds[buf][0];
    const float4* cpB = &lds[buf ^ 1][0];
#pragma unroll
    for (int d = 0; d < 4; ++d) {
      GROUP(A, B, cpA + 8 * (2 * d + 1), tb + 16 * d + 7);
      GROUP(B, A, (d < 3) ? (cpA + 8 * (2 * d + 2)) : cpB, tb + 16 * d + 15);
    }
    buf ^= 1;
  }

  // tail: n in [0,63] remaining steps, immediate renorm per 8
  {
    const int n = Tin - tb;
    const float4* cp = &lds[buf][0];
#pragma unroll
    for (int grp = 0; grp < 8; ++grp) {
      if (8 * grp >= n) break;  // wave-uniform
      float4 g[8];
#pragma unroll
      for (int i = 0; i < 8; ++i) g[i] = cp[8 * grp + i];
#pragma unroll
      for (int i = 0; i < 8; ++i) {
        if (8 * grp + i >= n) break;  // wave-uniform
        STEP(g[i]);
      }
      if (8 * grp + 8 <= n) {
        SNAP(tb + 8 * grp + 7);
        TREE;
        APPLY;
      }
    }
  }

  // readout: ll = log(alpha[2L] + alpha[2L-1]) + off*ln2
  const int r1 = 2 * L, r2 = 2 * L - 1;
  const float w1 = (r1 & 2) ? a2 : a0;  // even state -> reg 0 or 2
  const float w2 = (r2 & 2) ? a3 : a1;  // odd state  -> reg 1 or 3
  const float aL = rdl(w1, r1 >> 2);
  const float aL1 = rdl(w2, r2 >> 2);
  const float ssum = aL + aL1;
  float val = 0.0f;
  if (ssum > 0.0f) {
    const int bits = __float_as_int(ssum);
    const int ex = ((bits >> 23) & 255) - 126;
    const float mant = __int_as_float((bits & 0x007fffff) | 0x3f000000);
    const double ll2 = (double)(ex + off) + (double)log2f(mant);
    double ld = -ll2 * LN2d;
    if (ld > 0.5e30) ld = 0.0;  // zero_infinity
    val = (float)(ld / (double)L) * (1.0f / (float)NPAIR);
  }
  if (lane == 0) part[p] = val;
#undef STEP
#undef SNAP
#undef TREE
#undef APPLY
#undef GROUP
}

__global__ __launch_bounds__(256) void sctc_reduce(const float* __restrict__ ws,
                                                   float* __restrict__ out) {
  const int tid = threadIdx.x;
  float s = 0.0f;
  for (int i = tid; i < NPAIR; i += 256) s += ws[i];
  for (int o = 32; o >= 1; o >>= 1) s += __shfl_down(s, o);
  __shared__ float partial[4];
  if ((tid & 63) == 0) partial[tid >> 6] = s;
  __syncthreads();
  if (tid == 0) out[0] = partial[0] + partial[1] + partial[2] + partial[3];
}

extern "C" void kernel_launch(void* const* d_in, const int* in_sizes, int n_in,
                              void* d_out, int out_size, void* d_ws,
                              size_t ws_size, hipStream_t stream) {
  const float* logits = (const float*)d_in[0];
  const float* blank_logit = (const float*)d_in[1];
  const int* targets = (const int*)d_in[2];
  const int* in_len = (const int*)d_in[3];
  const int* tgt_len = (const int*)d_in[4];
  float* part = (float*)d_ws;
  float* out = (float*)d_out;

  sctc_scan<<<NPAIR, 64, 0, stream>>>(logits, blank_logit, targets, in_len,
                                      tgt_len, part);
  sctc_reduce<<<1, 256, 0, stream>>>(part, out);
}

// Round 10
// 28.295 us; speedup vs baseline: 2.3519x; 1.1081x over previous
//
#include <hip/hip_runtime.h>
#include <math.h>

// SCTC-SB loss, round 10 = round 9 (fwd/bwd split) + combine-dot mask fix:
// out-of-band fwd alphas (e > 2L) can overflow to +inf (excluded from renorm
// max by design); beta/gamma is exactly 0 there, and inf*0=NaN poisoned the
// dot. Mask alpha to e<=2L before the multiply.

#define LOG2E 1.4426950408889634f
#define LN2d 0.69314718055994530942

constexpr int Bc = 16, Tc = 500, Sc = 100, Fc = 35;
constexpr int NPAIR = Bc * Fc;  // 560
constexpr int EXPB = 217;       // renorm target biased exponent (2^90)

__device__ __forceinline__ float dpp_shr1(float v) {  // lane l <- l-1, fill 0
  return __int_as_float(__builtin_amdgcn_update_dpp(
      0, __float_as_int(v), 0x138, 0xF, 0xF, false));
}
__device__ __forceinline__ float dpp_shl1(float v) {  // lane l <- l+1, fill 0
  return __int_as_float(__builtin_amdgcn_update_dpp(
      0, __float_as_int(v), 0x130, 0xF, 0xF, false));
}
template <int C>
__device__ __forceinline__ int dppmax(int v) {
  int t = __builtin_amdgcn_update_dpp(v, v, C, 0xF, 0xF, false);
  return max(v, t);
}

// 3-class softmax -> float4(q2, q0, q1-q0, 0); x in log2 domain via *LOG2E
__device__ __forceinline__ float4 smf(float xr, float bl2) {
  const float x = xr * LOG2E;
  const float m = fmaxf(fabsf(x), bl2);
  const float u0 = exp2f(-x - m), u1 = exp2f(x - m), u2 = exp2f(bl2 - m);
  const float rz = 1.0f / (u0 + u1 + u2);
  return make_float4(u2 * rz, u0 * rz, (u1 - u0) * rz, 0.0f);
}

// One direction of the scan. BWD=false: alpha, t = tstart + i (tstart=1).
// BWD=true: beta, t = tstart - i (tstart=Tin-2). N steps. States in
// a0..a3 (lane l holds e=4l..4l+3), pre-initialized by caller at scale 2^90.
template <bool BWD>
__device__ __forceinline__ void scan_dir(
    const float* __restrict__ lg, float bl2, int Tin, int L, int N,
    int tstart, float bt0f, float bt1f, float skXf, float skYf, int lane,
    float4 (*stg)[64], float& A0, float& A1, float& A2, float& A3,
    int& offOut) {
  float a0 = A0, a1 = A1, a2 = A2, a3 = A3;
  int off = -90;
  int mm = 0;

  const int e_hi = 2 * L + 1, twoLm1 = 2 * L - 1;
  const int e0 = 4 * lane;
  const bool in0 = e0 <= e_hi, in1 = e0 + 1 <= e_hi, in2 = e0 + 2 <= e_hi,
             in3 = e0 + 3 <= e_hi;

  auto addr = [&](int i) -> int {  // step index -> clamped time index
    if (BWD) return max(tstart - i, 0);
    return min(tstart + i, Tc - 1);
  };

  auto step = [&](const float4& G) {
    const float po0 = fmaf(bt0f, G.z, G.y);
    const float po1 = fmaf(bt1f, G.z, G.y);
    if constexpr (!BWD) {
      const float pr3 = dpp_shr1(a3);  // alpha[4l-1]
      const float s01 = a0 + a1, s12 = a1 + a2, s23 = a2 + a3;
      const float t0v = a0 + pr3;
      const float t1v = fmaf(pr3, skXf, s01);
      const float t3v = fmaf(a1, skYf, s23);
      a0 = t0v * G.x; a1 = t1v * po0; a2 = s12 * G.x; a3 = t3v * po1;
    } else {
      const float nb0 = dpp_shl1(a0);  // beta[4l+4]
      const float nb1 = dpp_shl1(a1);  // beta[4l+5]
      const float s01 = a0 + a1, s12 = a1 + a2, s23 = a2 + a3;
      const float t1v = fmaf(a3, skXf, s12);
      const float t3v = fmaf(nb1, skYf, a3 + nb0);
      a0 = s01 * G.x; a1 = t1v * po0; a2 = s23 * G.x; a3 = t3v * po1;
    }
  };

  auto snap = [&](int istep) {
    if constexpr (!BWD) {
      const int t = tstart + istep;
      const int elo = twoLm1 - 2 * (Tin - 1 - t);
      const int x0 = (in0 && e0 >= elo) ? (__float_as_int(a0) >> 23) : 0;
      const int x1 = (in1 && e0 + 1 >= elo) ? (__float_as_int(a1) >> 23) : 0;
      const int x2 = (in2 && e0 + 2 >= elo) ? (__float_as_int(a2) >> 23) : 0;
      const int x3 = (in3 && e0 + 3 >= elo) ? (__float_as_int(a3) >> 23) : 0;
      mm = max(max(x0, x1), max(x2, x3));
    } else {
      (void)istep;  // beta: states > 2L are exactly 0, safe unmasked
      const int x0 = __float_as_int(a0) >> 23, x1 = __float_as_int(a1) >> 23;
      const int x2 = __float_as_int(a2) >> 23, x3 = __float_as_int(a3) >> 23;
      mm = max(max(x0, x1), max(x2, x3));
    }
  };
  auto tree = [&]() {
    mm = dppmax<0x111>(mm); mm = dppmax<0x112>(mm); mm = dppmax<0x114>(mm);
    mm = dppmax<0x118>(mm); mm = dppmax<0x142>(mm); mm = dppmax<0x143>(mm);
  };
  auto apply = [&]() {
    const int mw = __builtin_amdgcn_readlane(mm, 63);
    int k = EXPB - mw;
    k = min(max(k, -126), 126);
    const float sc = __int_as_float((k + 127) << 23);
    a0 *= sc; a1 *= sc; a2 *= sc; a3 *= sc;
    off -= k;
  };
  auto group = [&](float4 (&P)[8], float4 (&Q)[8], const float4* src,
                   int ilast) {
#pragma unroll
    for (int i = 0; i < 8; ++i) Q[i] = src[i];
    step(P[0]);
    tree();
    step(P[1]); step(P[2]); step(P[3]);
    apply();
    step(P[4]); step(P[5]); step(P[6]); step(P[7]);
    snap(ilast);
  };

  // prologue: stage chunk0, preload raw for chunk1, load group0, snapshot
  float xraw = lg[addr(lane) * Fc];
  stg[0][lane] = smf(xraw, bl2);
  xraw = lg[addr(64 + lane) * Fc];
  float4 A[8], B[8];
#pragma unroll
  for (int i = 0; i < 8; ++i) A[i] = stg[0][i];
  snap(-1);

  int buf = 0, ib = 0;
  for (; ib + 64 <= N; ib += 64) {
    if (ib + 64 < N) {
      stg[buf ^ 1][lane] = smf(xraw, bl2);
      xraw = lg[addr(ib + 128 + lane) * Fc];
    }
    const float4* cpA = &stg[buf][0];
    const float4* cpB = &stg[buf ^ 1][0];
#pragma unroll
    for (int d = 0; d < 4; ++d) {
      group(A, B, cpA + 8 * (2 * d + 1), ib + 16 * d + 7);
      group(B, A, (d < 3) ? (cpA + 8 * (2 * d + 2)) : cpB, ib + 16 * d + 15);
    }
    buf ^= 1;
  }
  {  // tail: n in [0,63], immediate renorm per 8
    const int n = N - ib;
    const float4* cp = &stg[buf][0];
#pragma unroll
    for (int grp = 0; grp < 8; ++grp) {
      if (8 * grp >= n) break;  // wave-uniform
      float4 g[8];
#pragma unroll
      for (int i = 0; i < 8; ++i) g[i] = cp[8 * grp + i];
#pragma unroll
      for (int i = 0; i < 8; ++i) {
        if (8 * grp + i >= n) break;  // wave-uniform
        step(g[i]);
      }
      if (8 * grp + 8 <= n) { snap(ib + 8 * grp + 7); tree(); apply(); }
    }
  }
  A0 = a0; A1 = a1; A2 = a2; A3 = a3;
  offOut = off;
}

__global__ __launch_bounds__(128) void sctc_scan(
    const float* __restrict__ logits,       // (B,T,F)
    const float* __restrict__ blank_logit,  // (1,)
    const int* __restrict__ targets,        // (B,S,F) 0/1
    const int* __restrict__ in_len,         // (B,)
    const int* __restrict__ tgt_len,        // (B,)
    float* __restrict__ part) {             // (NPAIR,)
  __shared__ float4 stg[2][2][64];  // [wave][dbuf][lane]
  __shared__ float4 xch[64];
  __shared__ int offsh;
  const int tid = threadIdx.x, wid = tid >> 6, lane = tid & 63;
  const int p = blockIdx.x;
  const int b = p / Fc, f = p - b * Fc;
  const int Tin = in_len[b];  // uniform
  const int L = tgt_len[b];   // uniform
  const float bl2 = blank_logit[0] * LOG2E;
  const float* __restrict__ lg = logits + (size_t)b * Tc * Fc + f;
  const float S90 = __int_as_float((90 + 127) << 23);
  const int e0 = 4 * lane;

  const int tbase = b * Sc * Fc + f;
  const int t0 = targets[tbase + min(2 * lane, Sc - 1) * Fc];
  const int t1 = targets[tbase + min(2 * lane + 1, Sc - 1) * Fc];
  const int tprev = __shfl_up(t1, 1);     // tgt[2l-1]
  const int tnext0 = __shfl_down(t0, 1);  // tgt[2l+2]
  const float bt0f = t0 ? 1.0f : 0.0f, bt1f = t1 ? 1.0f : 0.0f;
  const float sk1f = (lane == 0 || t0 != tprev) ? 1.0f : 0.0f;
  const float sk3f = (t1 != t0) ? 1.0f : 0.0f;
  const float skBf = (tnext0 != t1) ? 1.0f : 0.0f;

  const int tm = Tin >> 1;
  const int NF = tm;            // fwd steps: t = 1..tm
  const int NB = Tin - 2 - tm;  // bwd steps: t = Tin-2..tm+1

  float a0 = 0.0f, a1 = 0.0f, a2 = 0.0f, a3 = 0.0f;
  int off = -90;

  if (wid == 0) {  // forward alpha
    const float4 c0 = smf(lg[0], bl2);
    if (lane == 0) {
      a0 = c0.x * S90;
      a1 = fmaf(bt0f, c0.z, c0.y) * S90;
    }
    scan_dir<false>(lg, bl2, Tin, L, NF, 1, bt0f, bt1f, sk1f, sk3f, lane,
                    stg[0], a0, a1, a2, a3, off);
  } else {  // backward beta
    const float4 cE = smf(lg[(Tin - 1) * Fc], bl2);
    if (e0 == 2 * L) a0 = cE.x * S90;
    if (e0 + 2 == 2 * L) a2 = cE.x * S90;
    if (e0 + 1 == 2 * L - 1) a1 = fmaf(bt0f, cE.z, cE.y) * S90;
    if (e0 + 3 == 2 * L - 1) a3 = fmaf(bt1f, cE.z, cE.y) * S90;
    scan_dir<true>(lg, bl2, Tin, L, NB, Tin - 2, bt0f, bt1f, sk3f, skBf,
                   lane, stg[1], a0, a1, a2, a3, off);
    // gamma half-step: transition sum of beta_{tm+1} without emission probs
    const float nb0 = dpp_shl1(a0), nb1 = dpp_shl1(a1);
    const float bt0v = a0 + a1;
    const float bt1v = fmaf(a3, sk3f, a1 + a2);
    const float bt2v = a2 + a3;
    const float bt3v = fmaf(nb1, skBf, a3 + nb0);
    xch[lane] = make_float4(bt0v, bt1v, bt2v, bt3v);
    if (lane == 0) offsh = off;
  }
  __syncthreads();
  if (wid == 0) {
    const float4 bb = xch[lane];
    // FIX: mask alpha to states e <= 2L. Out-of-band alphas (e > 2L+1) may
    // be +inf (excluded from renorm max); gamma there is exactly 0, and
    // inf*0 = NaN would poison the dot. States > 2L contribute 0 anyway.
    const int twoL = 2 * L;
    const float z0 = (e0 <= twoL) ? a0 : 0.0f;
    const float z1 = (e0 + 1 <= twoL) ? a1 : 0.0f;
    const float z2 = (e0 + 2 <= twoL) ? a2 : 0.0f;
    const float z3 = (e0 + 3 <= twoL) ? a3 : 0.0f;
    double d = (double)z0 * bb.x + (double)z1 * bb.y + (double)z2 * bb.z +
               (double)z3 * bb.w;
    for (int o = 32; o >= 1; o >>= 1) d += __shfl_down(d, o);
    if (lane == 0) {
      const int offT = off + offsh;
      float val = 0.0f;
      if (d > 0.0) {
        int ex;
        const double mant = frexp(d, &ex);
        const double ll2 = (double)(ex + offT) + log2(mant);
        double ld = -ll2 * LN2d;
        if (ld > 0.5e30) ld = 0.0;  // zero_infinity
        val = (float)(ld / (double)L) * (1.0f / (float)NPAIR);
      }
      part[p] = val;
    }
  }
}

__global__ __launch_bounds__(256) void sctc_reduce(const float* __restrict__ ws,
                                                   float* __restrict__ out) {
  const int tid = threadIdx.x;
  float s = 0.0f;
  for (int i = tid; i < NPAIR; i += 256) s += ws[i];
  for (int o = 32; o >= 1; o >>= 1) s += __shfl_down(s, o);
  __shared__ float partial[4];
  if ((tid & 63) == 0) partial[tid >> 6] = s;
  __syncthreads();
  if (tid == 0) out[0] = partial[0] + partial[1] + partial[2] + partial[3];
}

extern "C" void kernel_launch(void* const* d_in, const int* in_sizes, int n_in,
                              void* d_out, int out_size, void* d_ws,
                              size_t ws_size, hipStream_t stream) {
  const float* logits = (const float*)d_in[0];
  const float* blank_logit = (const float*)d_in[1];
  const int* targets = (const int*)d_in[2];
  const int* in_len = (const int*)d_in[3];
  const int* tgt_len = (const int*)d_in[4];
  float* part = (float*)d_ws;
  float* out = (float*)d_out;

  sctc_scan<<<NPAIR, 128, 0, stream>>>(logits, blank_logit, targets, in_len,
                                       tgt_len, part);
  sctc_reduce<<<1, 256, 0, stream>>>(part, out);
}